// Round 1
// baseline (204.704 us; speedup 1.0000x reference)
//
#include <hip/hip_runtime.h>
#include <hip/hip_bf16.h>

#define DD 256
#define CC 104

typedef __bf16 bf16x8 __attribute__((ext_vector_type(8)));
typedef float  f32x4  __attribute__((ext_vector_type(4)));

__device__ inline float bu2f(unsigned short u) {
    return __uint_as_float(((unsigned)u) << 16);
}
__device__ inline unsigned short f2bu(float f) {
    __hip_bfloat16 h = __float2bfloat16(f);
    return *reinterpret_cast<unsigned short*>(&h);
}

// ---------------------------------------------------------------------------
// Kernel 1: prep — per-edge boundaries/tokens + W,Wc -> bf16 fragment order.
// Fragment layout (g = group, s = lane, j<8):
//   frag[g*512 + s*8 + j] = Wsrc[(nt*16 + (s&15))*256 + k0*32 + (s>>4)*8 + j]
//   W: g = k0*16 + nt (8 x 16);  Wc: g = k0*8 + nt (8 x 8, rows padded to 128)
// ---------------------------------------------------------------------------
__global__ void prep_all(
    const int* __restrict__ token_id,
    const int* __restrict__ src_idx,
    const int* __restrict__ dst_idx,
    int* __restrict__ seg_start,
    int* __restrict__ seg_end,
    int* __restrict__ edge_tok,
    int E, int PB,
    const float* __restrict__ W,
    const float* __restrict__ Wc,
    __hip_bfloat16* __restrict__ Wfrag,
    __hip_bfloat16* __restrict__ Wcfrag)
{
    const int b = blockIdx.x;
    const int t = threadIdx.x;
    if (b < PB) {
        int e = b * 256 + t;
        if (e >= E) return;
        int d = dst_idx[e];
        edge_tok[e] = token_id[src_idx[e]];
        if (e == 0 || dst_idx[e - 1] != d) seg_start[d] = e;
        if (e == E - 1 || dst_idx[e + 1] != d) seg_end[d] = e + 1;
        return;
    }
    if (b < PB + 32) {                      // W fragment reorder
        int idx  = (b - PB) * 256 + t;      // 0..8191
        int lane = idx & 63, g = idx >> 6;  // g = k0*16 + nt
        int nt = g & 15, k0 = g >> 4;
        int r = nt * 16 + (lane & 15);
        int c = k0 * 32 + (lane >> 4) * 8;
        const float* src = W + (size_t)r * DD + c;
        float4 v0 = *(const float4*)(src);
        float4 v1 = *(const float4*)(src + 4);
        uint4 pk;
        pk.x = (unsigned)f2bu(v0.x) | ((unsigned)f2bu(v0.y) << 16);
        pk.y = (unsigned)f2bu(v0.z) | ((unsigned)f2bu(v0.w) << 16);
        pk.z = (unsigned)f2bu(v1.x) | ((unsigned)f2bu(v1.y) << 16);
        pk.w = (unsigned)f2bu(v1.z) | ((unsigned)f2bu(v1.w) << 16);
        *(uint4*)(Wfrag + (size_t)idx * 8) = pk;
        return;
    }
    {                                       // Wc fragment reorder (padded)
        int idx  = (b - PB - 32) * 256 + t; // 0..4095
        int lane = idx & 63, g = idx >> 6;  // g = k0*8 + nt
        int nt = g & 7, k0 = g >> 3;
        int r = nt * 16 + (lane & 15);      // 0..127
        int c = k0 * 32 + (lane >> 4) * 8;
        float4 v0 = make_float4(0.f,0.f,0.f,0.f);
        float4 v1 = make_float4(0.f,0.f,0.f,0.f);
        if (r < CC) {
            const float* src = Wc + (size_t)r * DD + c;
            v0 = *(const float4*)(src);
            v1 = *(const float4*)(src + 4);
        }
        uint4 pk;
        pk.x = (unsigned)f2bu(v0.x) | ((unsigned)f2bu(v0.y) << 16);
        pk.y = (unsigned)f2bu(v0.z) | ((unsigned)f2bu(v0.w) << 16);
        pk.z = (unsigned)f2bu(v1.x) | ((unsigned)f2bu(v1.y) << 16);
        pk.w = (unsigned)f2bu(v1.z) | ((unsigned)f2bu(v1.w) << 16);
        *(uint4*)(Wcfrag + (size_t)idx * 8) = pk;
    }
}

// ---------------------------------------------------------------------------
// Kernel 2: We = emb @ W^T for ALL tokens (dense streaming MFMA GEMM).
// Also emits embb (bf16 emb) as a side product of the rows it streams.
// Block = 4 waves x 16 rows = 64 token rows; W staged in 4 x 32KB phases
// (straight copy of frag-ordered Wfrag). Swapped operands:
//   mfma(A=W-frag, B=emb-frag) -> lane's D = We[row=vb+l16][nt*16+quad*4+r]
// ---------------------------------------------------------------------------
__global__ __launch_bounds__(256, 3) void we_gemm(
    const float* __restrict__ emb,             // [V,256] fp32
    const __hip_bfloat16* __restrict__ Wfrag,  // 128 groups x 512
    __hip_bfloat16* __restrict__ Webuf,        // [V,256] bf16 out
    __hip_bfloat16* __restrict__ embb,         // [V,256] bf16 out
    int V)
{
    __shared__ __hip_bfloat16 lds[32 * 512];   // 32KB
    const int t    = threadIdx.x;
    const int lane = t & 63;
    const int w    = t >> 6;
    const int quad = lane >> 4;
    const int l16  = lane & 15;
    const int mrow = blockIdx.x * 64 + w * 16 + l16;
    const int row  = min(mrow, V - 1);

    // stream emb row fp32 -> bf16 frags (+ embb side-write)
    bf16x8 bfrag[8];
#pragma unroll
    for (int k0 = 0; k0 < 8; ++k0) {
        const float* src = emb + (size_t)row * DD + k0 * 32 + quad * 8;
        float4 v0 = *(const float4*)(src);
        float4 v1 = *(const float4*)(src + 4);
        uint4 pk;
        pk.x = (unsigned)f2bu(v0.x) | ((unsigned)f2bu(v0.y) << 16);
        pk.y = (unsigned)f2bu(v0.z) | ((unsigned)f2bu(v0.w) << 16);
        pk.z = (unsigned)f2bu(v1.x) | ((unsigned)f2bu(v1.y) << 16);
        pk.w = (unsigned)f2bu(v1.z) | ((unsigned)f2bu(v1.w) << 16);
        bfrag[k0] = *(bf16x8*)&pk;
        if (mrow < V)
            *(uint4*)(embb + (size_t)row * DD + k0 * 32 + quad * 8) = pk;
    }

    f32x4 acc[16];
#pragma unroll
    for (int nt = 0; nt < 16; ++nt) acc[nt] = (f32x4){0.f,0.f,0.f,0.f};

    for (int p = 0; p < 4; ++p) {
        if (p) __syncthreads();
        // straight-copy groups [32p, 32p+32): 32KB
#pragma unroll
        for (int it = 0; it < 8; ++it) {
            int idx = it * 256 + t;
            *(uint4*)(lds + (size_t)idx * 8) =
                *(const uint4*)(Wfrag + (size_t)p * 16384 + (size_t)idx * 8);
        }
        __syncthreads();
#pragma unroll
        for (int kl = 0; kl < 2; ++kl) {
            int k0 = p * 2 + kl;
#pragma unroll
            for (int nt = 0; nt < 16; ++nt) {
                bf16x8 wf = *(const bf16x8*)(lds + (kl * 16 + nt) * 512 + lane * 8);
                acc[nt] = __builtin_amdgcn_mfma_f32_16x16x32_bf16(wf, bfrag[k0], acc[nt], 0, 0, 0);
            }
        }
    }

    if (mrow < V) {
#pragma unroll
        for (int nt = 0; nt < 16; ++nt) {
            ushort4 o;
            o.x = f2bu(acc[nt][0]);
            o.y = f2bu(acc[nt][1]);
            o.z = f2bu(acc[nt][2]);
            o.w = f2bu(acc[nt][3]);
            *(ushort4*)(Webuf + (size_t)mrow * DD + nt * 16 + quad * 4) = o;
        }
    }
}

// ---------------------------------------------------------------------------
// Kernel 3: segment sum over We rows + FULL rnn epilogue.
// One wave per dst (50k waves -> max gather concurrency, the R8 lesson).
//   r = sum_{edges except last} We[tok]   (bf16 rows, fp32 accumulate)
//   ft = embb[last_tok] + (deg>1 ? relu(r + b) : 0)   -> bf16 ftb
// R9 restructure: the serial tail loop dominated each wave's runtime
// (~3.5 dependent ~800cy iterations for avg deg 16). Replace main+tail with
// 4 fully-unrolled PREDICATED 16-row blocks: all token loads issue in
// parallel, then 8 row-gathers per thread in flight; out-of-range rows clamp
// to token n-1 (cache-hit) and are EXEC-masked out of the accumulate.
// Last-message gather hoisted to the top to overlap the child gathers.
// ---------------------------------------------------------------------------
__global__ __launch_bounds__(256, 8) void seg_rnn_kernel(
                               const __hip_bfloat16* __restrict__ Webuf,
                               const __hip_bfloat16* __restrict__ embb,
                               const int* __restrict__ edge_tok,
                               const int* __restrict__ seg_start,
                               const int* __restrict__ seg_end,
                               const float* __restrict__ bvec,
                               __hip_bfloat16* __restrict__ ftb,
                               int n_dst)
{
    int w = (blockIdx.x * blockDim.x + threadIdx.x) >> 6;
    int lane = threadIdx.x & 63;
    if (w >= n_dst) return;
    int h   = lane >> 5;
    int l32 = lane & 31;
    int s  = seg_start[w];
    int e  = seg_end[w];
    int n  = e - 1 - s;                  // children to sum (deg-1)
    int lt = edge_tok[e - 1];            // last-edge token, issued first
    // early last-message gather: overlaps all child gathers below
    uint4 lm = *(const uint4*)(embb + (size_t)lt * DD + l32 * 8);
    bool gate = n > 0;
    int nfast = n < 64 ? n : 64;
    float acc[8] = {0.f,0.f,0.f,0.f,0.f,0.f,0.f,0.f};

#pragma unroll
    for (int bb = 0; bb < 4; ++bb) {
        int base = bb * 16;
        if (nfast > base) {              // wave-uniform branch
            uint4 uu[8];
#pragma unroll
            for (int k = 0; k < 8; ++k) {
                int r  = base + 2 * k + h;
                int rc = r < n - 1 ? r : n - 1;      // clamp -> valid token
                int tk = edge_tok[s + rc];
                uu[k] = *(const uint4*)(Webuf + (size_t)tk * DD + l32 * 8);
            }
#pragma unroll
            for (int k = 0; k < 8; ++k) {
                int r = base + 2 * k + h;
                if (r < nfast) {         // half-wave-uniform, EXEC-masked
                    const unsigned* ud = (const unsigned*)&uu[k];
#pragma unroll
                    for (int d = 0; d < 4; ++d) {
                        acc[2*d]   += __uint_as_float(ud[d] << 16);
                        acc[2*d+1] += __uint_as_float(ud[d] & 0xffff0000u);
                    }
                }
            }
        }
    }
    // rare overflow: segments with more than 64 children (deg > 65)
    for (int i = s + 64 + h; i < e - 1; i += 2) {
        int t0 = edge_tok[i];
        uint4 u = *(const uint4*)(Webuf + (size_t)t0 * DD + l32 * 8);
        const unsigned* ud = (const unsigned*)&u;
#pragma unroll
        for (int d = 0; d < 4; ++d) {
            acc[2*d]   += __uint_as_float(ud[d] << 16);
            acc[2*d+1] += __uint_as_float(ud[d] & 0xffff0000u);
        }
    }

#pragma unroll
    for (int j = 0; j < 8; ++j) acc[j] += __shfl_xor(acc[j], 32, 64);

    if (h == 0) {
        float4 b0 = *(const float4*)(bvec + l32 * 8);
        float4 b1 = *(const float4*)(bvec + l32 * 8 + 4);
        float bl[8] = {b0.x, b0.y, b0.z, b0.w, b1.x, b1.y, b1.z, b1.w};
        const unsigned* lmd = (const unsigned*)&lm;
        uint4 o;
        unsigned* od = (unsigned*)&o;
#pragma unroll
        for (int d = 0; d < 4; ++d) {
            float lo = __uint_as_float(lmd[d] << 16);
            float hi = __uint_as_float(lmd[d] & 0xffff0000u);
            float v0 = lo + (gate ? fmaxf(acc[2*d]   + bl[2*d],   0.f) : 0.f);
            float v1 = hi + (gate ? fmaxf(acc[2*d+1] + bl[2*d+1], 0.f) : 0.f);
            od[d] = (unsigned)f2bu(v0) | ((unsigned)f2bu(v1) << 16);
        }
        *(uint4*)(ftb + (size_t)w * DD + l32 * 8) = o;
    }
}

// ---------------------------------------------------------------------------
// Kernel 4: classifier GEMM. 64-row blocks, Wcfrag staged via straight
// 32KB copies (2 phases). Swapped operands -> float4 out stores.
// ---------------------------------------------------------------------------
__global__ __launch_bounds__(256, 4) void cls_mfma(
    const __hip_bfloat16* __restrict__ ftb,     // [M,256] bf16
    const __hip_bfloat16* __restrict__ Wcfrag,  // 64 groups x 512
    const float* __restrict__ bc,               // [104]
    float* __restrict__ out,                    // [M,104]
    int M)
{
    __shared__ __hip_bfloat16 lds[32 * 512];    // 32KB
    const int t    = threadIdx.x;
    const int lane = t & 63;
    const int w    = t >> 6;
    const int quad = lane >> 4;
    const int l16  = lane & 15;
    const int mw   = blockIdx.x * 64 + w * 16;

    int mrow = min(mw + l16, M - 1);
    bf16x8 ffrag[8];
    const __hip_bfloat16* arow = ftb + (size_t)mrow * DD + quad * 8;
#pragma unroll
    for (int k0 = 0; k0 < 8; ++k0)
        ffrag[k0] = *(const bf16x8*)(arow + k0 * 32);

    f32x4 acc[8];
#pragma unroll
    for (int nt = 0; nt < 8; ++nt) acc[nt] = (f32x4){0.f,0.f,0.f,0.f};

    for (int p = 0; p < 2; ++p) {
        if (p) __syncthreads();
#pragma unroll
        for (int it = 0; it < 8; ++it) {
            int idx = it * 256 + t;
            *(uint4*)(lds + (size_t)idx * 8) =
                *(const uint4*)(Wcfrag + (size_t)p * 16384 + (size_t)idx * 8);
        }
        __syncthreads();
#pragma unroll
        for (int kl = 0; kl < 4; ++kl) {
            int k0 = p * 4 + kl;
#pragma unroll
            for (int nt = 0; nt < 8; ++nt) {
                bf16x8 wf = *(const bf16x8*)(lds + (kl * 8 + nt) * 512 + lane * 8);
                acc[nt] = __builtin_amdgcn_mfma_f32_16x16x32_bf16(wf, ffrag[k0], acc[nt], 0, 0, 0);
            }
        }
    }

    int m = mw + l16;
    if (m < M) {
#pragma unroll
        for (int nt = 0; nt < 8; ++nt) {
            int c0 = nt * 16 + quad * 4;
            if (c0 <= 100) {
                float4 bia = *(const float4*)(bc + c0);
                float4 o;
                o.x = acc[nt][0] + bia.x;
                o.y = acc[nt][1] + bia.y;
                o.z = acc[nt][2] + bia.z;
                o.w = acc[nt][3] + bia.w;
                *(float4*)(out + (size_t)m * CC + c0) = o;
            }
        }
    }
}

// ---------------------------------------------------------------------------
extern "C" void kernel_launch(void* const* d_in, const int* in_sizes, int n_in,
                              void* d_out, int out_size, void* d_ws, size_t ws_size,
                              hipStream_t stream)
{
    const float* emb      = (const float*)d_in[0];
    const float* W        = (const float*)d_in[1];
    const float* bvec     = (const float*)d_in[2];
    const float* Wc       = (const float*)d_in[3];
    const float* bc       = (const float*)d_in[4];
    const int*   token_id = (const int*)d_in[5];
    const int*   src_idx  = (const int*)d_in[6];
    const int*   dst_idx  = (const int*)d_in[7];
    float*       out      = (float*)d_out;

    const int E     = in_sizes[6];
    const int Vemb  = in_sizes[0] / DD;
    const int n_dst = out_size / CC;
    (void)n_in; (void)ws_size;

    char* ws = (char*)d_ws;
    size_t off = 0;
    auto alloc = [&](size_t bytes) {
        void* p = ws + off;
        off = (off + bytes + 255) & ~(size_t)255;
        return p;
    };
    int* seg_start = (int*)alloc((size_t)n_dst * sizeof(int));
    int* seg_end   = (int*)alloc((size_t)n_dst * sizeof(int));
    int* edge_tok  = (int*)alloc((size_t)E * sizeof(int));
    __hip_bfloat16* embb   = (__hip_bfloat16*)alloc((size_t)Vemb * DD * 2);
    __hip_bfloat16* Webuf  = (__hip_bfloat16*)alloc((size_t)Vemb * DD * 2);
    __hip_bfloat16* ftb    = (__hip_bfloat16*)alloc((size_t)n_dst * DD * 2);
    __hip_bfloat16* Wfrag  = (__hip_bfloat16*)alloc((size_t)128 * 512 * 2);
    __hip_bfloat16* Wcfrag = (__hip_bfloat16*)alloc((size_t)64 * 512 * 2);

    const int PB = (E + 255) / 256;
    const int we_blocks  = (Vemb + 63) / 64;
    const int cls_blocks = (n_dst + 63) / 64;

    prep_all<<<PB + 48, 256, 0, stream>>>(
        token_id, src_idx, dst_idx, seg_start, seg_end, edge_tok, E, PB,
        W, Wc, Wfrag, Wcfrag);
    we_gemm<<<we_blocks, 256, 0, stream>>>(
        emb, Wfrag, Webuf, embb, Vemb);
    seg_rnn_kernel<<<(n_dst + 3) / 4, 256, 0, stream>>>(
        Webuf, embb, edge_tok, seg_start, seg_end, bvec, ftb, n_dst);
    cls_mfma<<<cls_blocks, 256, 0, stream>>>(
        ftb, Wcfrag, bc, out, n_dst);
}

// Round 2
// 195.593 us; speedup vs baseline: 1.0466x; 1.0466x over previous
//
#include <hip/hip_runtime.h>
#include <hip/hip_bf16.h>

#define DD 256
#define CC 104

typedef __bf16 bf16x8 __attribute__((ext_vector_type(8)));
typedef float  f32x4  __attribute__((ext_vector_type(4)));

__device__ inline float bu2f(unsigned short u) {
    return __uint_as_float(((unsigned)u) << 16);
}
__device__ inline unsigned short f2bu(float f) {
    __hip_bfloat16 h = __float2bfloat16(f);
    return *reinterpret_cast<unsigned short*>(&h);
}

// ---------------------------------------------------------------------------
// Kernel 1: prep — per-edge boundaries/tokens + W,Wc -> bf16 fragment order.
// Fragment layout (g = group, s = lane, j<8):
//   frag[g*512 + s*8 + j] = Wsrc[(nt*16 + (s&15))*256 + k0*32 + (s>>4)*8 + j]
//   W: g = k0*16 + nt (8 x 16);  Wc: g = k0*8 + nt (8 x 8, rows padded to 128)
// ---------------------------------------------------------------------------
__global__ void prep_all(
    const int* __restrict__ token_id,
    const int* __restrict__ src_idx,
    const int* __restrict__ dst_idx,
    int* __restrict__ seg_start,
    int* __restrict__ seg_end,
    int* __restrict__ edge_tok,
    int E, int PB,
    const float* __restrict__ W,
    const float* __restrict__ Wc,
    __hip_bfloat16* __restrict__ Wfrag,
    __hip_bfloat16* __restrict__ Wcfrag)
{
    const int b = blockIdx.x;
    const int t = threadIdx.x;
    if (b < PB) {
        int e = b * 256 + t;
        if (e >= E) return;
        int d = dst_idx[e];
        edge_tok[e] = token_id[src_idx[e]];
        if (e == 0 || dst_idx[e - 1] != d) seg_start[d] = e;
        if (e == E - 1 || dst_idx[e + 1] != d) seg_end[d] = e + 1;
        return;
    }
    if (b < PB + 32) {                      // W fragment reorder
        int idx  = (b - PB) * 256 + t;      // 0..8191
        int lane = idx & 63, g = idx >> 6;  // g = k0*16 + nt
        int nt = g & 15, k0 = g >> 4;
        int r = nt * 16 + (lane & 15);
        int c = k0 * 32 + (lane >> 4) * 8;
        const float* src = W + (size_t)r * DD + c;
        float4 v0 = *(const float4*)(src);
        float4 v1 = *(const float4*)(src + 4);
        uint4 pk;
        pk.x = (unsigned)f2bu(v0.x) | ((unsigned)f2bu(v0.y) << 16);
        pk.y = (unsigned)f2bu(v0.z) | ((unsigned)f2bu(v0.w) << 16);
        pk.z = (unsigned)f2bu(v1.x) | ((unsigned)f2bu(v1.y) << 16);
        pk.w = (unsigned)f2bu(v1.z) | ((unsigned)f2bu(v1.w) << 16);
        *(uint4*)(Wfrag + (size_t)idx * 8) = pk;
        return;
    }
    {                                       // Wc fragment reorder (padded)
        int idx  = (b - PB - 32) * 256 + t; // 0..4095
        int lane = idx & 63, g = idx >> 6;  // g = k0*8 + nt
        int nt = g & 7, k0 = g >> 3;
        int r = nt * 16 + (lane & 15);      // 0..127
        int c = k0 * 32 + (lane >> 4) * 8;
        float4 v0 = make_float4(0.f,0.f,0.f,0.f);
        float4 v1 = make_float4(0.f,0.f,0.f,0.f);
        if (r < CC) {
            const float* src = Wc + (size_t)r * DD + c;
            v0 = *(const float4*)(src);
            v1 = *(const float4*)(src + 4);
        }
        uint4 pk;
        pk.x = (unsigned)f2bu(v0.x) | ((unsigned)f2bu(v0.y) << 16);
        pk.y = (unsigned)f2bu(v0.z) | ((unsigned)f2bu(v0.w) << 16);
        pk.z = (unsigned)f2bu(v1.x) | ((unsigned)f2bu(v1.y) << 16);
        pk.w = (unsigned)f2bu(v1.z) | ((unsigned)f2bu(v1.w) << 16);
        *(uint4*)(Wcfrag + (size_t)idx * 8) = pk;
    }
}

// ---------------------------------------------------------------------------
// Kernel 2: We = emb @ W^T for ALL tokens (dense streaming MFMA GEMM).
// Also emits embb (bf16 emb) as a side product of the rows it streams.
// Block = 4 waves x 16 rows = 64 token rows; W staged in 4 x 32KB phases
// (straight copy of frag-ordered Wfrag). Swapped operands:
//   mfma(A=W-frag, B=emb-frag) -> lane's D = We[row=vb+l16][nt*16+quad*4+r]
// ---------------------------------------------------------------------------
__global__ __launch_bounds__(256, 3) void we_gemm(
    const float* __restrict__ emb,             // [V,256] fp32
    const __hip_bfloat16* __restrict__ Wfrag,  // 128 groups x 512
    __hip_bfloat16* __restrict__ Webuf,        // [V,256] bf16 out
    __hip_bfloat16* __restrict__ embb,         // [V,256] bf16 out
    int V)
{
    __shared__ __hip_bfloat16 lds[32 * 512];   // 32KB
    const int t    = threadIdx.x;
    const int lane = t & 63;
    const int w    = t >> 6;
    const int quad = lane >> 4;
    const int l16  = lane & 15;
    const int mrow = blockIdx.x * 64 + w * 16 + l16;
    const int row  = min(mrow, V - 1);

    // stream emb row fp32 -> bf16 frags (+ embb side-write)
    bf16x8 bfrag[8];
#pragma unroll
    for (int k0 = 0; k0 < 8; ++k0) {
        const float* src = emb + (size_t)row * DD + k0 * 32 + quad * 8;
        float4 v0 = *(const float4*)(src);
        float4 v1 = *(const float4*)(src + 4);
        uint4 pk;
        pk.x = (unsigned)f2bu(v0.x) | ((unsigned)f2bu(v0.y) << 16);
        pk.y = (unsigned)f2bu(v0.z) | ((unsigned)f2bu(v0.w) << 16);
        pk.z = (unsigned)f2bu(v1.x) | ((unsigned)f2bu(v1.y) << 16);
        pk.w = (unsigned)f2bu(v1.z) | ((unsigned)f2bu(v1.w) << 16);
        bfrag[k0] = *(bf16x8*)&pk;
        if (mrow < V)
            *(uint4*)(embb + (size_t)row * DD + k0 * 32 + quad * 8) = pk;
    }

    f32x4 acc[16];
#pragma unroll
    for (int nt = 0; nt < 16; ++nt) acc[nt] = (f32x4){0.f,0.f,0.f,0.f};

    for (int p = 0; p < 4; ++p) {
        if (p) __syncthreads();
        // straight-copy groups [32p, 32p+32): 32KB
#pragma unroll
        for (int it = 0; it < 8; ++it) {
            int idx = it * 256 + t;
            *(uint4*)(lds + (size_t)idx * 8) =
                *(const uint4*)(Wfrag + (size_t)p * 16384 + (size_t)idx * 8);
        }
        __syncthreads();
#pragma unroll
        for (int kl = 0; kl < 2; ++kl) {
            int k0 = p * 2 + kl;
#pragma unroll
            for (int nt = 0; nt < 16; ++nt) {
                bf16x8 wf = *(const bf16x8*)(lds + (kl * 16 + nt) * 512 + lane * 8);
                acc[nt] = __builtin_amdgcn_mfma_f32_16x16x32_bf16(wf, bfrag[k0], acc[nt], 0, 0, 0);
            }
        }
    }

    if (mrow < V) {
#pragma unroll
        for (int nt = 0; nt < 16; ++nt) {
            ushort4 o;
            o.x = f2bu(acc[nt][0]);
            o.y = f2bu(acc[nt][1]);
            o.z = f2bu(acc[nt][2]);
            o.w = f2bu(acc[nt][3]);
            *(ushort4*)(Webuf + (size_t)mrow * DD + nt * 16 + quad * 4) = o;
        }
    }
}

// ---------------------------------------------------------------------------
// Kernel 3: segment sum over We rows + FULL rnn epilogue.
// One wave per dst (50k waves -> max gather concurrency, the R8 lesson).
//   r = sum_{edges except last} We[tok]   (bf16 rows, fp32 accumulate)
//   ft = embb[last_tok] + (deg>1 ? relu(r + b) : 0)   -> bf16 ftb
// R9 restructure: 4 fully-unrolled PREDICATED 16-row blocks, all gathers of
// a block in flight; clamp out-of-range rows to a cached row, EXEC-mask the
// accumulate. R10 fix: launch_bounds(256,8) capped VGPRs at 64 -> uu[8]
// spilled to scratch (+50MB HBM writes, +16MB fetch, dur 51->63us).
// Relax to (256,4): ~70 live VGPRs fit in the 128 cap, no spill, natural
// occupancy ~7 waves/SIMD.
// ---------------------------------------------------------------------------
__global__ __launch_bounds__(256, 4) void seg_rnn_kernel(
                               const __hip_bfloat16* __restrict__ Webuf,
                               const __hip_bfloat16* __restrict__ embb,
                               const int* __restrict__ edge_tok,
                               const int* __restrict__ seg_start,
                               const int* __restrict__ seg_end,
                               const float* __restrict__ bvec,
                               __hip_bfloat16* __restrict__ ftb,
                               int n_dst)
{
    int w = (blockIdx.x * blockDim.x + threadIdx.x) >> 6;
    int lane = threadIdx.x & 63;
    if (w >= n_dst) return;
    int h   = lane >> 5;
    int l32 = lane & 31;
    int s  = seg_start[w];
    int e  = seg_end[w];
    int n  = e - 1 - s;                  // children to sum (deg-1)
    int lt = edge_tok[e - 1];            // last-edge token, issued first
    // early last-message gather: overlaps all child gathers below
    uint4 lm = *(const uint4*)(embb + (size_t)lt * DD + l32 * 8);
    bool gate = n > 0;
    int nfast = n < 64 ? n : 64;
    float acc[8] = {0.f,0.f,0.f,0.f,0.f,0.f,0.f,0.f};

#pragma unroll
    for (int bb = 0; bb < 4; ++bb) {
        int base = bb * 16;
        if (nfast > base) {              // wave-uniform branch
            uint4 uu[8];
#pragma unroll
            for (int k = 0; k < 8; ++k) {
                int r  = base + 2 * k + h;
                int rc = r < n - 1 ? r : n - 1;      // clamp -> valid token
                int tk = edge_tok[s + rc];
                uu[k] = *(const uint4*)(Webuf + (size_t)tk * DD + l32 * 8);
            }
#pragma unroll
            for (int k = 0; k < 8; ++k) {
                int r = base + 2 * k + h;
                if (r < nfast) {         // half-wave-uniform, EXEC-masked
                    const unsigned* ud = (const unsigned*)&uu[k];
#pragma unroll
                    for (int d = 0; d < 4; ++d) {
                        acc[2*d]   += __uint_as_float(ud[d] << 16);
                        acc[2*d+1] += __uint_as_float(ud[d] & 0xffff0000u);
                    }
                }
            }
        }
    }
    // rare overflow: segments with more than 64 children (deg > 65)
    for (int i = s + 64 + h; i < e - 1; i += 2) {
        int t0 = edge_tok[i];
        uint4 u = *(const uint4*)(Webuf + (size_t)t0 * DD + l32 * 8);
        const unsigned* ud = (const unsigned*)&u;
#pragma unroll
        for (int d = 0; d < 4; ++d) {
            acc[2*d]   += __uint_as_float(ud[d] << 16);
            acc[2*d+1] += __uint_as_float(ud[d] & 0xffff0000u);
        }
    }

#pragma unroll
    for (int j = 0; j < 8; ++j) acc[j] += __shfl_xor(acc[j], 32, 64);

    if (h == 0) {
        float4 b0 = *(const float4*)(bvec + l32 * 8);
        float4 b1 = *(const float4*)(bvec + l32 * 8 + 4);
        float bl[8] = {b0.x, b0.y, b0.z, b0.w, b1.x, b1.y, b1.z, b1.w};
        const unsigned* lmd = (const unsigned*)&lm;
        uint4 o;
        unsigned* od = (unsigned*)&o;
#pragma unroll
        for (int d = 0; d < 4; ++d) {
            float lo = __uint_as_float(lmd[d] << 16);
            float hi = __uint_as_float(lmd[d] & 0xffff0000u);
            float v0 = lo + (gate ? fmaxf(acc[2*d]   + bl[2*d],   0.f) : 0.f);
            float v1 = hi + (gate ? fmaxf(acc[2*d+1] + bl[2*d+1], 0.f) : 0.f);
            od[d] = (unsigned)f2bu(v0) | ((unsigned)f2bu(v1) << 16);
        }
        *(uint4*)(ftb + (size_t)w * DD + l32 * 8) = o;
    }
}

// ---------------------------------------------------------------------------
// Kernel 4: classifier GEMM. 64-row blocks, Wcfrag staged via straight
// 32KB copies (2 phases). Swapped operands -> float4 out stores.
// ---------------------------------------------------------------------------
__global__ __launch_bounds__(256, 4) void cls_mfma(
    const __hip_bfloat16* __restrict__ ftb,     // [M,256] bf16
    const __hip_bfloat16* __restrict__ Wcfrag,  // 64 groups x 512
    const float* __restrict__ bc,               // [104]
    float* __restrict__ out,                    // [M,104]
    int M)
{
    __shared__ __hip_bfloat16 lds[32 * 512];    // 32KB
    const int t    = threadIdx.x;
    const int lane = t & 63;
    const int w    = t >> 6;
    const int quad = lane >> 4;
    const int l16  = lane & 15;
    const int mw   = blockIdx.x * 64 + w * 16;

    int mrow = min(mw + l16, M - 1);
    bf16x8 ffrag[8];
    const __hip_bfloat16* arow = ftb + (size_t)mrow * DD + quad * 8;
#pragma unroll
    for (int k0 = 0; k0 < 8; ++k0)
        ffrag[k0] = *(const bf16x8*)(arow + k0 * 32);

    f32x4 acc[8];
#pragma unroll
    for (int nt = 0; nt < 8; ++nt) acc[nt] = (f32x4){0.f,0.f,0.f,0.f};

    for (int p = 0; p < 2; ++p) {
        if (p) __syncthreads();
#pragma unroll
        for (int it = 0; it < 8; ++it) {
            int idx = it * 256 + t;
            *(uint4*)(lds + (size_t)idx * 8) =
                *(const uint4*)(Wcfrag + (size_t)p * 16384 + (size_t)idx * 8);
        }
        __syncthreads();
#pragma unroll
        for (int kl = 0; kl < 4; ++kl) {
            int k0 = p * 4 + kl;
#pragma unroll
            for (int nt = 0; nt < 8; ++nt) {
                bf16x8 wf = *(const bf16x8*)(lds + (kl * 8 + nt) * 512 + lane * 8);
                acc[nt] = __builtin_amdgcn_mfma_f32_16x16x32_bf16(wf, ffrag[k0], acc[nt], 0, 0, 0);
            }
        }
    }

    int m = mw + l16;
    if (m < M) {
#pragma unroll
        for (int nt = 0; nt < 8; ++nt) {
            int c0 = nt * 16 + quad * 4;
            if (c0 <= 100) {
                float4 bia = *(const float4*)(bc + c0);
                float4 o;
                o.x = acc[nt][0] + bia.x;
                o.y = acc[nt][1] + bia.y;
                o.z = acc[nt][2] + bia.z;
                o.w = acc[nt][3] + bia.w;
                *(float4*)(out + (size_t)m * CC + c0) = o;
            }
        }
    }
}

// ---------------------------------------------------------------------------
extern "C" void kernel_launch(void* const* d_in, const int* in_sizes, int n_in,
                              void* d_out, int out_size, void* d_ws, size_t ws_size,
                              hipStream_t stream)
{
    const float* emb      = (const float*)d_in[0];
    const float* W        = (const float*)d_in[1];
    const float* bvec     = (const float*)d_in[2];
    const float* Wc       = (const float*)d_in[3];
    const float* bc       = (const float*)d_in[4];
    const int*   token_id = (const int*)d_in[5];
    const int*   src_idx  = (const int*)d_in[6];
    const int*   dst_idx  = (const int*)d_in[7];
    float*       out      = (float*)d_out;

    const int E     = in_sizes[6];
    const int Vemb  = in_sizes[0] / DD;
    const int n_dst = out_size / CC;
    (void)n_in; (void)ws_size;

    char* ws = (char*)d_ws;
    size_t off = 0;
    auto alloc = [&](size_t bytes) {
        void* p = ws + off;
        off = (off + bytes + 255) & ~(size_t)255;
        return p;
    };
    int* seg_start = (int*)alloc((size_t)n_dst * sizeof(int));
    int* seg_end   = (int*)alloc((size_t)n_dst * sizeof(int));
    int* edge_tok  = (int*)alloc((size_t)E * sizeof(int));
    __hip_bfloat16* embb   = (__hip_bfloat16*)alloc((size_t)Vemb * DD * 2);
    __hip_bfloat16* Webuf  = (__hip_bfloat16*)alloc((size_t)Vemb * DD * 2);
    __hip_bfloat16* ftb    = (__hip_bfloat16*)alloc((size_t)n_dst * DD * 2);
    __hip_bfloat16* Wfrag  = (__hip_bfloat16*)alloc((size_t)128 * 512 * 2);
    __hip_bfloat16* Wcfrag = (__hip_bfloat16*)alloc((size_t)64 * 512 * 2);

    const int PB = (E + 255) / 256;
    const int we_blocks  = (Vemb + 63) / 64;
    const int cls_blocks = (n_dst + 63) / 64;

    prep_all<<<PB + 48, 256, 0, stream>>>(
        token_id, src_idx, dst_idx, seg_start, seg_end, edge_tok, E, PB,
        W, Wc, Wfrag, Wcfrag);
    we_gemm<<<we_blocks, 256, 0, stream>>>(
        emb, Wfrag, Webuf, embb, Vemb);
    seg_rnn_kernel<<<(n_dst + 3) / 4, 256, 0, stream>>>(
        Webuf, embb, edge_tok, seg_start, seg_end, bvec, ftb, n_dst);
    cls_mfma<<<cls_blocks, 256, 0, stream>>>(
        ftb, Wcfrag, bc, out, n_dst);
}